// Round 1
// baseline (267.511 us; speedup 1.0000x reference)
//
#include <hip/hip_runtime.h>
#include <hip/hip_bf16.h>

// RandomShift: out[row, t] = x[row, t - s] if 0 <= t-s < T else 0
// x: [B*M, T] float32 (B=32, M=8, T=160000), shifts: [B*M] int32 in [0, 2*16000]
// s = shifts[row] - 16000.
// Memory-bound shifted copy. float4 aligned stores; 4 predicated scalar loads
// (load side is misaligned by row-uniform s; consecutive lanes still cover
// contiguous bytes so cache-line utilization is full across the 4 loads).

constexpr int T_LEN     = 160000;
constexpr int MAX_SHIFT = 16000;   // int(T * 0.1)
constexpr int ROWS      = 32 * 8;  // B * M

__global__ __launch_bounds__(256) void RandomShift_33079838113837_kernel(
    const float* __restrict__ x,
    const int*   __restrict__ shifts,
    float*       __restrict__ out) {
    const int row = blockIdx.y;                    // 0..ROWS-1, wave-uniform
    const int s   = shifts[row] - MAX_SHIFT;       // row-uniform shift

    const float* __restrict__ xr   = x   + (size_t)row * T_LEN;
    float*       __restrict__ outr = out + (size_t)row * T_LEN;

    const int t0 = (blockIdx.x * blockDim.x + threadIdx.x) * 4;
    if (t0 >= T_LEN) return;                       // T_LEN % 4 == 0, no partial vec

    const int src0 = t0 - s;

    float r[4];
#pragma unroll
    for (int j = 0; j < 4; ++j) {
        const int src = src0 + j;
        r[j] = (src >= 0 && src < T_LEN) ? xr[src] : 0.0f;
    }

    *reinterpret_cast<float4*>(outr + t0) = make_float4(r[0], r[1], r[2], r[3]);
}

extern "C" void kernel_launch(void* const* d_in, const int* in_sizes, int n_in,
                              void* d_out, int out_size, void* d_ws, size_t ws_size,
                              hipStream_t stream) {
    const float* x      = (const float*)d_in[0];
    const int*   shifts = (const int*)d_in[1];
    float*       out    = (float*)d_out;

    const int vec_per_row = T_LEN / 4;                     // 40000
    const int block = 256;
    dim3 grid((vec_per_row + block - 1) / block, ROWS, 1); // 157 x 256

    RandomShift_33079838113837_kernel<<<grid, block, 0, stream>>>(x, shifts, out);
}